// Round 4
// baseline (172.248 us; speedup 1.0000x reference)
//
#include <hip/hip_runtime.h>
#include <cstdint>
#include <cstddef>

#define S_LEN 2047
#define BATCH 8
#define R_TOT 1162
#define NCHUNK 8
#define NEGV (-1e9f)
#define NROWS (BATCH * S_LEN)          // 16376
#define N4 4757228                     // NROWS*R_TOT/4 float4s (exact)
#define MWORDS 37                      // ceil(1162/32)

// ws layout: local = 8*2047*6*4 = 393,024 B at 0,
//            carry = 8*8*6*4   =   1,536 B at 393,024,
//            mtab  = 16376*37*4 = 2,423,648 B at 394,560 (only if ws_size allows).
#define CARRY_OFF 393024
#define MTAB_OFF  394560
#define WS_NEED   (MTAB_OFF + (size_t)NROWS * MWORDS * 4)

__device__ __constant__ int d_numerators[12] = {1, 2, 3, 4, 5, 6, 7, 8, 9, 10, 12, 16};

// ---------------------------------------------------------------------------
// Kernel 1: within-chunk inclusive scan. VERBATIM verified.
// ---------------------------------------------------------------------------
__global__ __launch_bounds__(256) void scan_local(const int* __restrict__ song,
                                                  unsigned* __restrict__ local) {
    const int b = blockIdx.x >> 3;
    const int c = blockIdx.x & 7;
    const int tid = threadIdx.x;
    const int j = c * 256 + tid;
    __shared__ unsigned lds_f[3][256];
    __shared__ unsigned lds_inst[5][256];
    const unsigned HAS = 1u << 16;
    const long base = (long)b * S_LEN;

    unsigned e_f[3] = {0, 0, 0};
    unsigned e_inst[5] = {0, 0, 0, 0, 0};
    if (j < S_LEN) {
        const int* rj = song + (base + j) * 11;
        const int type = rj[0];
        if (type == 4)      e_f[0] = HAS | (unsigned)rj[8];
        else if (type == 5) e_f[1] = HAS | (unsigned)rj[9];
        else if (type == 6) e_f[2] = HAS | (unsigned)rj[10];
        else if (type == 1) { const int v = rj[6]; e_inst[v >> 5] = 1u << (v & 31); }
    }
#pragma unroll
    for (int w = 0; w < 3; w++) lds_f[w][tid] = e_f[w];
#pragma unroll
    for (int w = 0; w < 5; w++) lds_inst[w][tid] = e_inst[w];
    __syncthreads();

    for (int off = 1; off < 256; off <<= 1) {
        unsigned p_f[3] = {0, 0, 0};
        unsigned p_inst[5] = {0, 0, 0, 0, 0};
        if (tid >= off) {
#pragma unroll
            for (int w = 0; w < 3; w++) p_f[w] = lds_f[w][tid - off];
#pragma unroll
            for (int w = 0; w < 5; w++) p_inst[w] = lds_inst[w][tid - off];
        }
        __syncthreads();
        if (tid >= off) {
#pragma unroll
            for (int w = 0; w < 3; w++) {
                if (!(e_f[w] & HAS)) e_f[w] = p_f[w];
                lds_f[w][tid] = e_f[w];
            }
#pragma unroll
            for (int w = 0; w < 5; w++) {
                e_inst[w] |= p_inst[w];
                lds_inst[w][tid] = e_inst[w];
            }
        }
        __syncthreads();
    }

    if (j < S_LEN) {
        const unsigned w0 =
            (e_f[0] & 0xFFu) | ((e_f[1] & 0xFFu) << 8) | ((e_f[2] & 0xFFu) << 16) |
            (((e_f[0] >> 16) & 1u) << 24) | (((e_f[1] >> 16) & 1u) << 25) |
            (((e_f[2] >> 16) & 1u) << 26);
        unsigned* sp = local + (size_t)(base + j) * 6;
        sp[0] = w0;
#pragma unroll
        for (int w = 0; w < 5; w++) sp[1 + w] = e_inst[w];
    }
}

// ---------------------------------------------------------------------------
// Kernel 2: exclusive per-chunk carries. VERBATIM verified.
// ---------------------------------------------------------------------------
__global__ __launch_bounds__(64) void scan_carry(const int* __restrict__ song,
                                                 const unsigned* __restrict__ local,
                                                 unsigned* __restrict__ carry) {
    const int b = threadIdx.x;
    if (b >= BATCH) return;
    const int* r0 = song + (size_t)b * S_LEN * 11;
    unsigned cks = (unsigned)r0[8], cts = (unsigned)r0[9], ctp = (unsigned)r0[10];
    unsigned chas = 0;
    unsigned cinst[5] = {0, 0, 0, 0, 0};
    for (int c = 0; c < NCHUNK; c++) {
        unsigned* cp = carry + ((size_t)b * NCHUNK + c) * 6;
        cp[0] = (cks & 0xFFu) | ((cts & 0xFFu) << 8) | ((ctp & 0xFFu) << 16) | (chas << 24);
#pragma unroll
        for (int w = 0; w < 5; w++) cp[1 + w] = cinst[w];
        const int pos = min((c + 1) * 256, S_LEN) - 1;
        const unsigned* lp = local + ((size_t)b * S_LEN + pos) * 6;
        const unsigned a0 = lp[0];
        if ((a0 >> 24) & 1u) cks = a0 & 0xFFu;
        if ((a0 >> 25) & 1u) cts = (a0 >> 8) & 0xFFu;
        if ((a0 >> 26) & 1u) ctp = (a0 >> 16) & 0xFFu;
        chas |= (a0 >> 24) & 7u;
#pragma unroll
        for (int w = 0; w < 5; w++) cinst[w] |= lp[1 + w];
    }
}

// ---------------------------------------------------------------------------
// Kernel 3a (new path): per-row STATE kernel. Verbatim round-3 state/argmax/
// f_info logic, but instead of masking the 76 MB score stream it emits the
// row's 1162-bit column mask (37 words) via __ballot of the verbatim maskf.
//   t in {0,2,7}: all-ones words, zero barriers, zero score loads.
//   t != 3      : no score loads (candidates only feed the t==3 argmax).
//   t == 3      : loads only cols 0..271 (1.1 KB) for the argmax.
// ---------------------------------------------------------------------------
__global__ __launch_bounds__(256) void row_state(const int* __restrict__ song,
                                                 const int* __restrict__ ctype,
                                                 const float* __restrict__ scores,
                                                 const unsigned* __restrict__ local,
                                                 const unsigned* __restrict__ carry,
                                                 unsigned* __restrict__ mtab) {
    const int row = blockIdx.x;
    const int tid = threadIdx.x;
    const int b = row / S_LEN;
    const int i = row - b * S_LEN;

    __shared__ float s_val[128];
    __shared__ int   s_idx[128];
    __shared__ float sb_val[8];
    __shared__ int   sb_idx[8];
    __shared__ int   s_info[10];
    __shared__ int   f_info[17];

    const int t0 = ctype[row];
    unsigned* mrow = mtab + (size_t)row * MWORDS;

    // ---- fast path: all masks all-true ----
    if (t0 == 0 || t0 == 2 || t0 == 7) {
        if (tid < MWORDS) mrow[tid] = 0xFFFFFFFFu;
        return;
    }

    const size_t rbase = (size_t)row * R_TOT;
    const float2* s2 = (const float2*)(scores + rbase);

    if (t0 == 3 && tid < 136) {
        const float2 r0 = s2[tid];
        if (tid < 128) {
            // measure candidates: cols 2*tid, 2*tid+1 (first index wins ties)
            const bool sec = (r0.y > r0.x);
            s_val[tid] = sec ? r0.y : r0.x;
            s_idx[tid] = 2 * tid + (sec ? 1 : 0);
        } else {
            // beat candidates: beat-relative cols 2*(tid-128), +1
            const bool sec = (r0.y > r0.x);
            sb_val[tid - 128] = sec ? r0.y : r0.x;
            sb_idx[tid - 128] = (2 * tid - 256) + (sec ? 1 : 0);
        }
    }
    if (tid >= 136 && tid < 142) {
        const int w = tid - 136;
        const int e = min(i + 1, S_LEN - 1);
        const unsigned lw = local[((size_t)b * S_LEN + e) * 6 + w];
        const unsigned cw = carry[((size_t)b * NCHUNK + (e >> 8)) * 6 + w];
        unsigned v;
        if (w == 0) {
            const unsigned ks = ((lw >> 24) & 1u) ? (lw & 0xFFu) : (cw & 0xFFu);
            const unsigned ts = ((lw >> 25) & 1u) ? ((lw >> 8) & 0xFFu) : ((cw >> 8) & 0xFFu);
            const unsigned tp = ((lw >> 26) & 1u) ? ((lw >> 16) & 0xFFu) : ((cw >> 16) & 0xFFu);
            const unsigned hks = ((lw >> 24) | (cw >> 24)) & 1u;
            const unsigned hts = ((lw >> 25) | (cw >> 25)) & 1u;
            v = ks | (ts << 8) | (tp << 16) | (hks << 24) | (hts << 25);
        } else {
            v = lw | cw;
        }
        s_info[w] = (int)v;
    } else if (tid >= 142 && tid < 146) {
        const int* srow = song + (size_t)row * 11;
        if (tid == 142) s_info[6] = srow[1];
        if (tid == 143) s_info[7] = srow[2];
        if (tid == 144) s_info[8] = srow[3];
        if (tid == 145) s_info[9] = ctype[row];
    }
    __syncthreads();

    // 7-barrier reduction tree: only the t==3 path consumes pred_m/pred_b.
    if (t0 == 3) {
        for (int s = 64; s > 0; s >>= 1) {
            if (tid < s) {
                if (s_val[tid + s] > s_val[tid]) {  // strict > keeps lower index on tie
                    s_val[tid] = s_val[tid + s];
                    s_idx[tid] = s_idx[tid + s];
                }
            }
            __syncthreads();
        }
    }

    if (tid == 0) {
        int pred_m = -1, pred_b = -1;  // t!=3: never matches song fields (>=0)
        if (t0 == 3) {
            pred_m = s_idx[0];
            float bv = sb_val[0];
            pred_b = sb_idx[0];
#pragma unroll
            for (int q = 1; q < 8; q++) {
                if (sb_val[q] > bv) { bv = sb_val[q]; pred_b = sb_idx[q]; }
            }
        }
        const unsigned pack = (unsigned)s_info[0];
        const int song1 = s_info[6], song2 = s_info[7], song3 = s_info[8];
        const int t = s_info[9];
        const bool c1 = (pred_m == song1);
        const int min_beat = c1 ? song2 : 0;
        const bool c2 = c1 && (pred_b == min_beat);
        const int min_pos = c2 ? song3 : 0;
        const int last_ks = pack & 0xFF;
        const int last_ts = (pack >> 8) & 0xFF;
        const int last_tp = (pack >> 16) & 0xFF;
        f_info[0] = t;
        f_info[1] = song1;       // min_measure
        f_info[2] = min_beat;
        f_info[3] = min_pos;
        f_info[4] = (song2 == 0 && song3 == 0) ? song1 : song1 + 1;  // min_m46
        f_info[5] = d_numerators[last_ts % 12];                      // max_beat
        f_info[6] = last_ks;
        f_info[7] = last_ts;
        f_info[8] = last_tp;
        f_info[9]  = (int)((pack >> 24) & 1u);  // has_ks
        f_info[10] = (int)((pack >> 25) & 1u);  // has_ts
        const unsigned u = (unsigned)s_info[1] | (unsigned)s_info[2] | (unsigned)s_info[3] |
                           (unsigned)s_info[4] | (unsigned)s_info[5];
        f_info[11] = (u != 0u);                 // has_inst
        f_info[12] = s_info[1]; f_info[13] = s_info[2]; f_info[14] = s_info[3];
        f_info[15] = s_info[4]; f_info[16] = s_info[5];
    }
    __syncthreads();

    const int t = f_info[0];
    const int min_measure = f_info[1], min_beat = f_info[2], min_pos = f_info[3];
    const int min_m46 = f_info[4], max_beat = f_info[5];
    const int last_ks = f_info[6], last_ts = f_info[7], last_tp = f_info[8];
    const bool has_ks = f_info[9] != 0, has_ts = f_info[10] != 0, has_inst = f_info[11] != 0;
    unsigned inst[5];
#pragma unroll
    for (int w = 0; w < 5; w++) inst[w] = (unsigned)f_info[12 + w];
    const bool is3 = (t == 3);
    const bool is46 = (t >= 4) && (t <= 6);

    auto maskf = [&](int col) -> bool {
        if (col < 256) {
            if (is3) return col >= min_measure;
            if (is46) return col >= min_m46;
            return true;
        } else if (col < 272) {
            if (!is3) return true;
            const int v = col - 256;
            return (v >= min_beat) && (v < max_beat);
        } else if (col < 400) {
            return is3 ? ((col - 272) >= min_pos) : true;
        } else if (col < 784) {
            return true;  // duration + pitch
        } else if (col < 913) {
            const int v = col - 784;
            const bool pres = ((inst[v >> 5] >> (v & 31)) & 1u) != 0u;
            if (is3) return pres;
            if (t == 1) return has_inst ? !pres : true;
            return true;
        } else if (col < 1041) {
            return true;  // velocity
        } else if (col < 1065) {
            const int v = col - 1041;
            if (is3) return v == last_ks;
            if (t == 4) return has_ks ? (v != last_ks) : true;
            return true;
        } else if (col < 1113) {
            const int v = col - 1065;
            if (is3) return v == last_ts;
            if (t == 5) return has_ts ? (v != last_ts) : true;
            return true;
        } else {
            const int v = col - 1113;
            if (is3) return v == last_tp;
            if (t == 6) return v != last_tp;  // no has-check for tempo
            return true;
        }
    };

    // Pack mask bits via wave ballots: wave wv, lane l, iteration it covers
    // col = it*256 + wv*64 + l; ballot bit l maps to mask word (colbase/32).
    const int wv = tid >> 6;
    const int lane = tid & 63;
#pragma unroll
    for (int it = 0; it < 5; it++) {
        const int colb = it * 256 + wv * 64;
        const int col = colb + lane;
        const bool pred = (col < R_TOT) ? maskf(col) : false;
        const unsigned long long m = __ballot(pred);
        const int w_idx = colb >> 5;
        if (lane == 0 && w_idx < MWORDS) mrow[w_idx] = (unsigned)m;
        if (lane == 1 && w_idx + 1 < MWORDS) mrow[w_idx + 1] = (unsigned)(m >> 32);
    }
}

// ---------------------------------------------------------------------------
// Kernel 4 (new path): pure streaming select. Grid-stride over float4s of the
// flat [NROWS*R_TOT] tensor (16 B/lane — fill-kernel access width). Each
// element tests its bit in the L2-resident mask table. R_TOT % 4 != 0, so a
// float4 may span a row boundary: col wraps, row increments (rare: 0.34%).
// ---------------------------------------------------------------------------
__global__ __launch_bounds__(256) void stream_mask(const float* __restrict__ scores,
                                                   const unsigned* __restrict__ mtab,
                                                   float* __restrict__ out) {
    const int stride = gridDim.x * 256;
    for (int f = blockIdx.x * 256 + threadIdx.x; f < N4; f += stride) {
        const unsigned fe = (unsigned)f * 4u;
        unsigned row = fe / 1162u;           // compiler magic-multiply
        unsigned col = fe - row * 1162u;
        const float4 v = ((const float4*)scores)[f];
        float4 w;
        {
            const unsigned bits = mtab[row * MWORDS + (col >> 5)];
            w.x = ((bits >> (col & 31u)) & 1u) ? v.x : NEGV;
            if (++col == 1162u) { col = 0u; ++row; }
        }
        {
            const unsigned bits = mtab[row * MWORDS + (col >> 5)];
            w.y = ((bits >> (col & 31u)) & 1u) ? v.y : NEGV;
            if (++col == 1162u) { col = 0u; ++row; }
        }
        {
            const unsigned bits = mtab[row * MWORDS + (col >> 5)];
            w.z = ((bits >> (col & 31u)) & 1u) ? v.z : NEGV;
            if (++col == 1162u) { col = 0u; ++row; }
        }
        {
            const unsigned bits = mtab[row * MWORDS + (col >> 5)];
            w.w = ((bits >> (col & 31u)) & 1u) ? v.w : NEGV;
        }
        ((float4*)out)[f] = w;
    }
}

// ---------------------------------------------------------------------------
// Fallback (verified round-3 mask kernel) — used only if ws_size < WS_NEED.
// ---------------------------------------------------------------------------
__global__ __launch_bounds__(256) void mask_kernel(const int* __restrict__ song,
                                                   const int* __restrict__ ctype,
                                                   const float* __restrict__ scores,
                                                   const unsigned* __restrict__ local,
                                                   const unsigned* __restrict__ carry,
                                                   float* __restrict__ out) {
    const int row = blockIdx.x;
    const int tid = threadIdx.x;
    const int b = row / S_LEN;
    const int i = row - b * S_LEN;

    __shared__ float s_val[128];
    __shared__ int   s_idx[128];
    __shared__ float sb_val[8];
    __shared__ int   sb_idx[8];
    __shared__ int   s_info[10];
    __shared__ int   f_info[17];

    const size_t rbase = (size_t)row * R_TOT;
    const float2* s2 = (const float2*)(scores + rbase);
    float2* o2 = (float2*)(out + rbase);

    const int t0 = ctype[row];

    const float2 r0 = s2[tid];
    const float2 r1 = s2[tid + 256];
    float2 r2 = make_float2(0.f, 0.f);
    if (tid < 69) r2 = s2[tid + 512];

    if (t0 == 0 || t0 == 2 || t0 == 7) {
        o2[tid] = r0;
        o2[tid + 256] = r1;
        if (tid < 69) o2[tid + 512] = r2;
        return;
    }

    if (tid < 128) {
        const bool sec = (r0.y > r0.x);
        s_val[tid] = sec ? r0.y : r0.x;
        s_idx[tid] = 2 * tid + (sec ? 1 : 0);
    } else if (tid < 136) {
        const bool sec = (r0.y > r0.x);
        sb_val[tid - 128] = sec ? r0.y : r0.x;
        sb_idx[tid - 128] = (2 * tid - 256) + (sec ? 1 : 0);
    } else if (tid < 142) {
        const int w = tid - 136;
        const int e = min(i + 1, S_LEN - 1);
        const unsigned lw = local[((size_t)b * S_LEN + e) * 6 + w];
        const unsigned cw = carry[((size_t)b * NCHUNK + (e >> 8)) * 6 + w];
        unsigned v;
        if (w == 0) {
            const unsigned ks = ((lw >> 24) & 1u) ? (lw & 0xFFu) : (cw & 0xFFu);
            const unsigned ts = ((lw >> 25) & 1u) ? ((lw >> 8) & 0xFFu) : ((cw >> 8) & 0xFFu);
            const unsigned tp = ((lw >> 26) & 1u) ? ((lw >> 16) & 0xFFu) : ((cw >> 16) & 0xFFu);
            const unsigned hks = ((lw >> 24) | (cw >> 24)) & 1u;
            const unsigned hts = ((lw >> 25) | (cw >> 25)) & 1u;
            v = ks | (ts << 8) | (tp << 16) | (hks << 24) | (hts << 25);
        } else {
            v = lw | cw;
        }
        s_info[w] = (int)v;
    } else if (tid < 146) {
        const int* srow = song + (size_t)row * 11;
        if (tid == 142) s_info[6] = srow[1];
        if (tid == 143) s_info[7] = srow[2];
        if (tid == 144) s_info[8] = srow[3];
        if (tid == 145) s_info[9] = ctype[row];
    }
    __syncthreads();

    if (t0 == 3) {
        for (int s = 64; s > 0; s >>= 1) {
            if (tid < s) {
                if (s_val[tid + s] > s_val[tid]) {
                    s_val[tid] = s_val[tid + s];
                    s_idx[tid] = s_idx[tid + s];
                }
            }
            __syncthreads();
        }
    }

    if (tid == 0) {
        int pred_m = -1, pred_b = -1;
        if (t0 == 3) {
            pred_m = s_idx[0];
            float bv = sb_val[0];
            pred_b = sb_idx[0];
#pragma unroll
            for (int q = 1; q < 8; q++) {
                if (sb_val[q] > bv) { bv = sb_val[q]; pred_b = sb_idx[q]; }
            }
        }
        const unsigned pack = (unsigned)s_info[0];
        const int song1 = s_info[6], song2 = s_info[7], song3 = s_info[8];
        const int t = s_info[9];
        const bool c1 = (pred_m == song1);
        const int min_beat = c1 ? song2 : 0;
        const bool c2 = c1 && (pred_b == min_beat);
        const int min_pos = c2 ? song3 : 0;
        const int last_ks = pack & 0xFF;
        const int last_ts = (pack >> 8) & 0xFF;
        const int last_tp = (pack >> 16) & 0xFF;
        f_info[0] = t;
        f_info[1] = song1;
        f_info[2] = min_beat;
        f_info[3] = min_pos;
        f_info[4] = (song2 == 0 && song3 == 0) ? song1 : song1 + 1;
        f_info[5] = d_numerators[last_ts % 12];
        f_info[6] = last_ks;
        f_info[7] = last_ts;
        f_info[8] = last_tp;
        f_info[9]  = (int)((pack >> 24) & 1u);
        f_info[10] = (int)((pack >> 25) & 1u);
        const unsigned u = (unsigned)s_info[1] | (unsigned)s_info[2] | (unsigned)s_info[3] |
                           (unsigned)s_info[4] | (unsigned)s_info[5];
        f_info[11] = (u != 0u);
        f_info[12] = s_info[1]; f_info[13] = s_info[2]; f_info[14] = s_info[3];
        f_info[15] = s_info[4]; f_info[16] = s_info[5];
    }
    __syncthreads();

    const int t = f_info[0];
    const int min_measure = f_info[1], min_beat = f_info[2], min_pos = f_info[3];
    const int min_m46 = f_info[4], max_beat = f_info[5];
    const int last_ks = f_info[6], last_ts = f_info[7], last_tp = f_info[8];
    const bool has_ks = f_info[9] != 0, has_ts = f_info[10] != 0, has_inst = f_info[11] != 0;
    unsigned inst[5];
#pragma unroll
    for (int w = 0; w < 5; w++) inst[w] = (unsigned)f_info[12 + w];
    const bool is3 = (t == 3);
    const bool is46 = (t >= 4) && (t <= 6);

    auto maskf = [&](int col) -> bool {
        if (col < 256) {
            if (is3) return col >= min_measure;
            if (is46) return col >= min_m46;
            return true;
        } else if (col < 272) {
            if (!is3) return true;
            const int v = col - 256;
            return (v >= min_beat) && (v < max_beat);
        } else if (col < 400) {
            return is3 ? ((col - 272) >= min_pos) : true;
        } else if (col < 784) {
            return true;
        } else if (col < 913) {
            const int v = col - 784;
            const bool pres = ((inst[v >> 5] >> (v & 31)) & 1u) != 0u;
            if (is3) return pres;
            if (t == 1) return has_inst ? !pres : true;
            return true;
        } else if (col < 1041) {
            return true;
        } else if (col < 1065) {
            const int v = col - 1041;
            if (is3) return v == last_ks;
            if (t == 4) return has_ks ? (v != last_ks) : true;
            return true;
        } else if (col < 1113) {
            const int v = col - 1065;
            if (is3) return v == last_ts;
            if (t == 5) return has_ts ? (v != last_ts) : true;
            return true;
        } else {
            const int v = col - 1113;
            if (is3) return v == last_tp;
            if (t == 6) return v != last_tp;
            return true;
        }
    };

    float2 w;
    int c = 2 * tid;
    w.x = maskf(c)     ? r0.x : NEGV;
    w.y = maskf(c + 1) ? r0.y : NEGV;
    o2[tid] = w;

    c = 512 + 2 * tid;
    w.x = maskf(c)     ? r1.x : NEGV;
    w.y = maskf(c + 1) ? r1.y : NEGV;
    o2[tid + 256] = w;

    if (tid < 69) {
        c = 1024 + 2 * tid;
        w.x = maskf(c)     ? r2.x : NEGV;
        w.y = maskf(c + 1) ? r2.y : NEGV;
        o2[tid + 512] = w;
    }
}

extern "C" void kernel_launch(void* const* d_in, const int* in_sizes, int n_in,
                              void* d_out, int out_size, void* d_ws, size_t ws_size,
                              hipStream_t stream) {
    const int* song = (const int*)d_in[0];
    const int* ctype = (const int*)d_in[1];
    const float* scores = (const float*)d_in[2];
    float* out = (float*)d_out;
    unsigned* local = (unsigned*)d_ws;                          // 393,024 B
    unsigned* carry = (unsigned*)((char*)d_ws + CARRY_OFF);     // 1,536 B

    scan_local<<<BATCH * NCHUNK, 256, 0, stream>>>(song, local);
    scan_carry<<<1, 64, 0, stream>>>(song, local, carry);

    if (ws_size >= WS_NEED) {
        unsigned* mtab = (unsigned*)((char*)d_ws + MTAB_OFF);   // 2,423,648 B
        row_state<<<NROWS, 256, 0, stream>>>(song, ctype, scores, local, carry, mtab);
        stream_mask<<<2048, 256, 0, stream>>>(scores, mtab, out);
    } else {
        // workspace too small for the mask table: verified round-3 path
        mask_kernel<<<NROWS, 256, 0, stream>>>(song, ctype, scores, local, carry, out);
    }
}

// Round 5
// 169.084 us; speedup vs baseline: 1.0187x; 1.0187x over previous
//
#include <hip/hip_runtime.h>
#include <cstdint>
#include <cstddef>

#define S_LEN 2047
#define BATCH 8
#define R_TOT 1162
#define NCHUNK 8
#define NEGV (-1e9f)
#define NROWS (BATCH * S_LEN)   // 16376 (even)
#define NPAIR (NROWS / 2)       // 8188 pairs; pair stride = 2324 floats = 581 float4

// ws layout: local = 8*2047*6*4 = 393,024 B at offset 0,
//            carry = 8*8*6*4 = 1,536 B at offset 393,024.
#define CARRY_OFF 393024

__device__ __constant__ int d_numerators[12] = {1, 2, 3, 4, 5, 6, 7, 8, 9, 10, 12, 16};

// ---------------------------------------------------------------------------
// Kernel 1: within-chunk inclusive scan. VERBATIM verified (rounds 0/3).
// ---------------------------------------------------------------------------
__global__ __launch_bounds__(256) void scan_local(const int* __restrict__ song,
                                                  unsigned* __restrict__ local) {
    const int b = blockIdx.x >> 3;
    const int c = blockIdx.x & 7;
    const int tid = threadIdx.x;
    const int j = c * 256 + tid;
    __shared__ unsigned lds_f[3][256];
    __shared__ unsigned lds_inst[5][256];
    const unsigned HAS = 1u << 16;
    const long base = (long)b * S_LEN;

    unsigned e_f[3] = {0, 0, 0};
    unsigned e_inst[5] = {0, 0, 0, 0, 0};
    if (j < S_LEN) {
        const int* rj = song + (base + j) * 11;
        const int type = rj[0];
        if (type == 4)      e_f[0] = HAS | (unsigned)rj[8];
        else if (type == 5) e_f[1] = HAS | (unsigned)rj[9];
        else if (type == 6) e_f[2] = HAS | (unsigned)rj[10];
        else if (type == 1) { const int v = rj[6]; e_inst[v >> 5] = 1u << (v & 31); }
    }
#pragma unroll
    for (int w = 0; w < 3; w++) lds_f[w][tid] = e_f[w];
#pragma unroll
    for (int w = 0; w < 5; w++) lds_inst[w][tid] = e_inst[w];
    __syncthreads();

    for (int off = 1; off < 256; off <<= 1) {
        unsigned p_f[3] = {0, 0, 0};
        unsigned p_inst[5] = {0, 0, 0, 0, 0};
        if (tid >= off) {
#pragma unroll
            for (int w = 0; w < 3; w++) p_f[w] = lds_f[w][tid - off];
#pragma unroll
            for (int w = 0; w < 5; w++) p_inst[w] = lds_inst[w][tid - off];
        }
        __syncthreads();
        if (tid >= off) {
#pragma unroll
            for (int w = 0; w < 3; w++) {
                if (!(e_f[w] & HAS)) e_f[w] = p_f[w];
                lds_f[w][tid] = e_f[w];
            }
#pragma unroll
            for (int w = 0; w < 5; w++) {
                e_inst[w] |= p_inst[w];
                lds_inst[w][tid] = e_inst[w];
            }
        }
        __syncthreads();
    }

    if (j < S_LEN) {
        const unsigned w0 =
            (e_f[0] & 0xFFu) | ((e_f[1] & 0xFFu) << 8) | ((e_f[2] & 0xFFu) << 16) |
            (((e_f[0] >> 16) & 1u) << 24) | (((e_f[1] >> 16) & 1u) << 25) |
            (((e_f[2] >> 16) & 1u) << 26);
        unsigned* sp = local + (size_t)(base + j) * 6;
        sp[0] = w0;
#pragma unroll
        for (int w = 0; w < 5; w++) sp[1 + w] = e_inst[w];
    }
}

// ---------------------------------------------------------------------------
// Kernel 2: exclusive per-chunk carries. VERBATIM verified (rounds 0/3).
// ---------------------------------------------------------------------------
__global__ __launch_bounds__(64) void scan_carry(const int* __restrict__ song,
                                                 const unsigned* __restrict__ local,
                                                 unsigned* __restrict__ carry) {
    const int b = threadIdx.x;
    if (b >= BATCH) return;
    const int* r0 = song + (size_t)b * S_LEN * 11;
    unsigned cks = (unsigned)r0[8], cts = (unsigned)r0[9], ctp = (unsigned)r0[10];
    unsigned chas = 0;  // bit0 has_ks, bit1 has_ts, bit2 has_tp
    unsigned cinst[5] = {0, 0, 0, 0, 0};
    for (int c = 0; c < NCHUNK; c++) {
        unsigned* cp = carry + ((size_t)b * NCHUNK + c) * 6;
        cp[0] = (cks & 0xFFu) | ((cts & 0xFFu) << 8) | ((ctp & 0xFFu) << 16) | (chas << 24);
#pragma unroll
        for (int w = 0; w < 5; w++) cp[1 + w] = cinst[w];
        const int pos = min((c + 1) * 256, S_LEN) - 1;
        const unsigned* lp = local + ((size_t)b * S_LEN + pos) * 6;
        const unsigned a0 = lp[0];
        if ((a0 >> 24) & 1u) cks = a0 & 0xFFu;
        if ((a0 >> 25) & 1u) cts = (a0 >> 8) & 0xFFu;
        if ((a0 >> 26) & 1u) ctp = (a0 >> 16) & 0xFFu;
        chas |= (a0 >> 24) & 7u;
#pragma unroll
        for (int w = 0; w < 5; w++) cinst[w] |= lp[1 + w];
    }
}

// ---------------------------------------------------------------------------
// Kernel 3: PAIR mask kernel. 8188 blocks x 512 threads; each 256-thread half
// runs the VERBATIM round-0 state phase for one row (LDS arrays indexed by
// half; tree runs unconditionally so halves stay barrier-lockstep; copy-type
// rows flow through the full path — maskf is all-true for t in {0,2,7}, as
// verified in round 0). Stream phase: the 2-row pair is 9296 B = 581 aligned
// float4 — 16 B/lane streaming. Both-copy pairs exit before the first barrier
// (block-uniform branch).
// f_info slots (verbatim round-0 finalize): [0]=t [1]=min_measure [2]=min_beat
// [3]=min_pos [4]=min_m46 [5]=max_beat [6]=last_ks [7]=last_ts [8]=last_tp
// [9]=has_ks [10]=has_ts [11]=has_inst [12..16]=inst[0..4]
// ---------------------------------------------------------------------------
__global__ __launch_bounds__(512) void mask_pair(const int* __restrict__ song,
                                                 const int* __restrict__ ctype,
                                                 const float* __restrict__ scores,
                                                 const unsigned* __restrict__ local,
                                                 const unsigned* __restrict__ carry,
                                                 float* __restrict__ out) {
    const int pair = blockIdx.x;
    const int tid = threadIdx.x;      // 0..511
    const int half = tid >> 8;        // 0 or 1
    const int th = tid & 255;         // thread index within half
    const int row = pair * 2 + half;

    __shared__ float s_val[2][128];
    __shared__ int   s_idx[2][128];
    __shared__ float sb_val[2][8];
    __shared__ int   sb_idx[2][8];
    __shared__ int   s_info[2][10];
    __shared__ int   f_info[2][17];

    const size_t pbase = (size_t)pair * (2 * R_TOT);          // floats
    const float4* s4 = (const float4*)(scores + pbase);       // 581 float4
    float4* o4 = (float4*)(out + pbase);

    const int tA = ctype[pair * 2];
    const int tB = ctype[pair * 2 + 1];
    const bool copyA = (tA == 0 || tA == 2 || tA == 7);
    const bool copyB = (tB == 0 || tB == 2 || tB == 7);

    // issue the pair's stream loads first
    float4 v0 = s4[tid];
    float4 v1 = make_float4(0.f, 0.f, 0.f, 0.f);
    if (tid < 69) v1 = s4[512 + tid];

    // ---- both rows all-true: pure float4 copy, zero barriers ----
    if (copyA && copyB) {
        o4[tid] = v0;
        if (tid < 69) o4[512 + tid] = v1;
        return;
    }

    // ================= state phase (verbatim round-0, per half) =============
    const int b = row / S_LEN;
    const int i = row - b * S_LEN;
    const size_t rbase = (size_t)row * R_TOT;
    const float2* s2 = (const float2*)(scores + rbase);

    if (th < 136) {
        const float2 r0 = s2[th];
        if (th < 128) {
            // measure candidates: cols 2*th, 2*th+1 (first index wins ties)
            const bool sec = (r0.y > r0.x);
            s_val[half][th] = sec ? r0.y : r0.x;
            s_idx[half][th] = 2 * th + (sec ? 1 : 0);
        } else {
            // beat candidates: beat-relative cols 2*(th-128), +1
            const bool sec = (r0.y > r0.x);
            sb_val[half][th - 128] = sec ? r0.y : r0.x;
            sb_idx[half][th - 128] = (2 * th - 256) + (sec ? 1 : 0);
        }
    } else if (th < 142) {
        const int w = th - 136;
        const int e = min(i + 1, S_LEN - 1);
        const unsigned lw = local[((size_t)b * S_LEN + e) * 6 + w];
        const unsigned cw = carry[((size_t)b * NCHUNK + (e >> 8)) * 6 + w];
        unsigned v;
        if (w == 0) {
            const unsigned ks = ((lw >> 24) & 1u) ? (lw & 0xFFu) : (cw & 0xFFu);
            const unsigned ts = ((lw >> 25) & 1u) ? ((lw >> 8) & 0xFFu) : ((cw >> 8) & 0xFFu);
            const unsigned tp = ((lw >> 26) & 1u) ? ((lw >> 16) & 0xFFu) : ((cw >> 16) & 0xFFu);
            const unsigned hks = ((lw >> 24) | (cw >> 24)) & 1u;
            const unsigned hts = ((lw >> 25) | (cw >> 25)) & 1u;
            v = ks | (ts << 8) | (tp << 16) | (hks << 24) | (hts << 25);
        } else {
            v = lw | cw;
        }
        s_info[half][w] = (int)v;
    } else if (th < 146) {
        const int* srow = song + (size_t)row * 11;
        if (th == 142) s_info[half][6] = srow[1];
        if (th == 143) s_info[half][7] = srow[2];
        if (th == 144) s_info[half][8] = srow[3];
        if (th == 145) s_info[half][9] = ctype[row];
    }
    __syncthreads();

    // unconditional 7-round tree (round-0 verified; keeps halves lockstep)
    for (int s = 64; s > 0; s >>= 1) {
        if (th < s) {
            if (s_val[half][th + s] > s_val[half][th]) {  // strict > keeps lower index
                s_val[half][th] = s_val[half][th + s];
                s_idx[half][th] = s_idx[half][th + s];
            }
        }
        __syncthreads();
    }

    if (th == 0) {
        const int pred_m = s_idx[half][0];
        float bv = sb_val[half][0];
        int pred_b = sb_idx[half][0];
#pragma unroll
        for (int q = 1; q < 8; q++) {
            if (sb_val[half][q] > bv) { bv = sb_val[half][q]; pred_b = sb_idx[half][q]; }
        }
        const unsigned pack = (unsigned)s_info[half][0];
        const int song1 = s_info[half][6], song2 = s_info[half][7], song3 = s_info[half][8];
        const int t = s_info[half][9];
        const bool c1 = (pred_m == song1);
        const int min_beat = c1 ? song2 : 0;
        const bool c2 = c1 && (pred_b == min_beat);
        const int min_pos = c2 ? song3 : 0;
        const int last_ks = pack & 0xFF;
        const int last_ts = (pack >> 8) & 0xFF;
        const int last_tp = (pack >> 16) & 0xFF;
        f_info[half][0] = t;
        f_info[half][1] = song1;       // min_measure
        f_info[half][2] = min_beat;
        f_info[half][3] = min_pos;
        f_info[half][4] = (song2 == 0 && song3 == 0) ? song1 : song1 + 1;  // min_m46
        f_info[half][5] = d_numerators[last_ts % 12];                      // max_beat
        f_info[half][6] = last_ks;
        f_info[half][7] = last_ts;
        f_info[half][8] = last_tp;
        f_info[half][9]  = (int)((pack >> 24) & 1u);  // has_ks
        f_info[half][10] = (int)((pack >> 25) & 1u);  // has_ts
        const unsigned u = (unsigned)s_info[half][1] | (unsigned)s_info[half][2] |
                           (unsigned)s_info[half][3] | (unsigned)s_info[half][4] |
                           (unsigned)s_info[half][5];
        f_info[half][11] = (u != 0u);                 // has_inst
        f_info[half][12] = s_info[half][1]; f_info[half][13] = s_info[half][2];
        f_info[half][14] = s_info[half][3]; f_info[half][15] = s_info[half][4];
        f_info[half][16] = s_info[half][5];
    }
    __syncthreads();

    // ================= stream phase: 581 float4 per pair ====================
    // maskf: verbatim round-0 lambda with fields read from f_info[r] (LDS).
    auto maskf = [&](int col, int r) -> bool {
        const int t = f_info[r][0];
        const bool is3 = (t == 3);
        if (col < 256) {
            if (is3) return col >= f_info[r][1];
            if (t >= 4 && t <= 6) return col >= f_info[r][4];
            return true;
        } else if (col < 272) {
            if (!is3) return true;
            const int v = col - 256;
            return (v >= f_info[r][2]) && (v < f_info[r][5]);
        } else if (col < 400) {
            return is3 ? ((col - 272) >= f_info[r][3]) : true;
        } else if (col < 784) {
            return true;  // duration + pitch
        } else if (col < 913) {
            const int v = col - 784;
            const bool pres = (((unsigned)f_info[r][12 + (v >> 5)] >> (v & 31)) & 1u) != 0u;
            if (is3) return pres;
            if (t == 1) return f_info[r][11] ? !pres : true;
            return true;
        } else if (col < 1041) {
            return true;  // velocity
        } else if (col < 1065) {
            const int v = col - 1041;
            if (is3) return v == f_info[r][6];
            if (t == 4) return f_info[r][9] ? (v != f_info[r][6]) : true;
            return true;
        } else if (col < 1113) {
            const int v = col - 1065;
            if (is3) return v == f_info[r][7];
            if (t == 5) return f_info[r][10] ? (v != f_info[r][7]) : true;
            return true;
        } else {
            const int v = col - 1113;
            if (is3) return v == f_info[r][8];
            if (t == 6) return v != f_info[r][8];  // no has-check for tempo
            return true;
        }
    };

    // q-th float4 covers pair-flat elements 4q..4q+3; element >= 1162 -> row B.
    {
        const int e = 4 * tid;
        float4 w;
        int col = e;       int r = (col >= R_TOT); col -= r ? R_TOT : 0;
        w.x = maskf(col, r) ? v0.x : NEGV;
        col = e + 1;       r = (col >= R_TOT); col -= r ? R_TOT : 0;
        w.y = maskf(col, r) ? v0.y : NEGV;
        col = e + 2;       r = (col >= R_TOT); col -= r ? R_TOT : 0;
        w.z = maskf(col, r) ? v0.z : NEGV;
        col = e + 3;       r = (col >= R_TOT); col -= r ? R_TOT : 0;
        w.w = maskf(col, r) ? v0.w : NEGV;
        o4[tid] = w;
    }
    if (tid < 69) {
        const int e = 4 * (512 + tid);   // 2048.. -> all row B (e >= 1162)
        float4 w;
        w.x = maskf(e     - R_TOT, 1) ? v1.x : NEGV;
        w.y = maskf(e + 1 - R_TOT, 1) ? v1.y : NEGV;
        w.z = maskf(e + 2 - R_TOT, 1) ? v1.z : NEGV;
        w.w = maskf(e + 3 - R_TOT, 1) ? v1.w : NEGV;
        o4[512 + tid] = w;
    }
}

extern "C" void kernel_launch(void* const* d_in, const int* in_sizes, int n_in,
                              void* d_out, int out_size, void* d_ws, size_t ws_size,
                              hipStream_t stream) {
    const int* song = (const int*)d_in[0];
    const int* ctype = (const int*)d_in[1];
    const float* scores = (const float*)d_in[2];
    float* out = (float*)d_out;
    unsigned* local = (unsigned*)d_ws;                          // 393,024 B
    unsigned* carry = (unsigned*)((char*)d_ws + CARRY_OFF);     // 1,536 B

    scan_local<<<BATCH * NCHUNK, 256, 0, stream>>>(song, local);
    scan_carry<<<1, 64, 0, stream>>>(song, local, carry);
    mask_pair<<<NPAIR, 512, 0, stream>>>(song, ctype, scores, local, carry, out);
}

// Round 6
// 157.637 us; speedup vs baseline: 1.0927x; 1.0726x over previous
//
#include <hip/hip_runtime.h>
#include <cstdint>
#include <cstddef>

#define S_LEN 2047
#define BATCH 8
#define R_TOT 1162
#define NCHUNK 8
#define NEGV (-1e9f)
#define NROWS (BATCH * S_LEN)   // 16376
#define MGRID 2048              // persistent mask blocks (8 blocks/CU resident)

// ws layout: local = 8*2047*6*4 = 393,024 B at offset 0,
//            carry = 8*8*6*4 = 1,536 B at offset 393,024.
#define CARRY_OFF 393024

__device__ __constant__ int d_numerators[12] = {1, 2, 3, 4, 5, 6, 7, 8, 9, 10, 12, 16};

// ---------------------------------------------------------------------------
// Kernel 1: within-chunk inclusive scan. VERBATIM verified (rounds 0/3).
// ---------------------------------------------------------------------------
__global__ __launch_bounds__(256) void scan_local(const int* __restrict__ song,
                                                  unsigned* __restrict__ local) {
    const int b = blockIdx.x >> 3;
    const int c = blockIdx.x & 7;
    const int tid = threadIdx.x;
    const int j = c * 256 + tid;
    __shared__ unsigned lds_f[3][256];
    __shared__ unsigned lds_inst[5][256];
    const unsigned HAS = 1u << 16;
    const long base = (long)b * S_LEN;

    unsigned e_f[3] = {0, 0, 0};
    unsigned e_inst[5] = {0, 0, 0, 0, 0};
    if (j < S_LEN) {
        const int* rj = song + (base + j) * 11;
        const int type = rj[0];
        if (type == 4)      e_f[0] = HAS | (unsigned)rj[8];
        else if (type == 5) e_f[1] = HAS | (unsigned)rj[9];
        else if (type == 6) e_f[2] = HAS | (unsigned)rj[10];
        else if (type == 1) { const int v = rj[6]; e_inst[v >> 5] = 1u << (v & 31); }
    }
#pragma unroll
    for (int w = 0; w < 3; w++) lds_f[w][tid] = e_f[w];
#pragma unroll
    for (int w = 0; w < 5; w++) lds_inst[w][tid] = e_inst[w];
    __syncthreads();

    for (int off = 1; off < 256; off <<= 1) {
        unsigned p_f[3] = {0, 0, 0};
        unsigned p_inst[5] = {0, 0, 0, 0, 0};
        if (tid >= off) {
#pragma unroll
            for (int w = 0; w < 3; w++) p_f[w] = lds_f[w][tid - off];
#pragma unroll
            for (int w = 0; w < 5; w++) p_inst[w] = lds_inst[w][tid - off];
        }
        __syncthreads();
        if (tid >= off) {
#pragma unroll
            for (int w = 0; w < 3; w++) {
                if (!(e_f[w] & HAS)) e_f[w] = p_f[w];
                lds_f[w][tid] = e_f[w];
            }
#pragma unroll
            for (int w = 0; w < 5; w++) {
                e_inst[w] |= p_inst[w];
                lds_inst[w][tid] = e_inst[w];
            }
        }
        __syncthreads();
    }

    if (j < S_LEN) {
        const unsigned w0 =
            (e_f[0] & 0xFFu) | ((e_f[1] & 0xFFu) << 8) | ((e_f[2] & 0xFFu) << 16) |
            (((e_f[0] >> 16) & 1u) << 24) | (((e_f[1] >> 16) & 1u) << 25) |
            (((e_f[2] >> 16) & 1u) << 26);
        unsigned* sp = local + (size_t)(base + j) * 6;
        sp[0] = w0;
#pragma unroll
        for (int w = 0; w < 5; w++) sp[1 + w] = e_inst[w];
    }
}

// ---------------------------------------------------------------------------
// Kernel 2: exclusive per-chunk carries. VERBATIM verified (rounds 0/3).
// ---------------------------------------------------------------------------
__global__ __launch_bounds__(64) void scan_carry(const int* __restrict__ song,
                                                 const unsigned* __restrict__ local,
                                                 unsigned* __restrict__ carry) {
    const int b = threadIdx.x;
    if (b >= BATCH) return;
    const int* r0 = song + (size_t)b * S_LEN * 11;
    unsigned cks = (unsigned)r0[8], cts = (unsigned)r0[9], ctp = (unsigned)r0[10];
    unsigned chas = 0;  // bit0 has_ks, bit1 has_ts, bit2 has_tp
    unsigned cinst[5] = {0, 0, 0, 0, 0};
    for (int c = 0; c < NCHUNK; c++) {
        unsigned* cp = carry + ((size_t)b * NCHUNK + c) * 6;
        cp[0] = (cks & 0xFFu) | ((cts & 0xFFu) << 8) | ((ctp & 0xFFu) << 16) | (chas << 24);
#pragma unroll
        for (int w = 0; w < 5; w++) cp[1 + w] = cinst[w];
        const int pos = min((c + 1) * 256, S_LEN) - 1;
        const unsigned* lp = local + ((size_t)b * S_LEN + pos) * 6;
        const unsigned a0 = lp[0];
        if ((a0 >> 24) & 1u) cks = a0 & 0xFFu;
        if ((a0 >> 25) & 1u) cts = (a0 >> 8) & 0xFFu;
        if ((a0 >> 26) & 1u) ctp = (a0 >> 16) & 0xFFu;
        chas |= (a0 >> 24) & 7u;
#pragma unroll
        for (int w = 0; w < 5; w++) cinst[w] |= lp[1 + w];
    }
}

// ---------------------------------------------------------------------------
// Kernel 3: PERSISTENT mask kernel. 2048 blocks x 256 threads; each block
// grid-strides over rows (~8 rows/block). Per-row logic is VERBATIM round-3
// (verified): copy rows {0,2,7} zero-barrier; t!=3 skips the tree; t==3 full
// 9-barrier path. New vs round-3 (structure only, no semantics):
//   - loop instead of one-row-per-block (keeps CU read stream fed),
//   - next row's 19 float2 prefetched into registers before the mask/store
//     phase (HBM latency hides under state barrier + mask + store),
//   - copy path falls through (no return); non-copy iterations end with one
//     __syncthreads to protect LDS reuse across iterations (t0 block-uniform
//     so all barriers stay block-uniform).
// ---------------------------------------------------------------------------
__global__ __launch_bounds__(256) void mask_kernel(const int* __restrict__ song,
                                                   const int* __restrict__ ctype,
                                                   const float* __restrict__ scores,
                                                   const unsigned* __restrict__ local,
                                                   const unsigned* __restrict__ carry,
                                                   float* __restrict__ out) {
    const int tid = threadIdx.x;

    __shared__ float s_val[128];
    __shared__ int   s_idx[128];
    __shared__ float sb_val[8];
    __shared__ int   sb_idx[8];
    __shared__ int   s_info[10];
    __shared__ int   f_info[17];

    int row = blockIdx.x;

    // preload first row's stream
    float2 r0, r1, r2;
    {
        const float2* s2 = (const float2*)(scores + (size_t)row * R_TOT);
        r0 = s2[tid];
        r1 = s2[tid + 256];
        r2 = make_float2(0.f, 0.f);
        if (tid < 69) r2 = s2[tid + 512];
    }

    while (row < NROWS) {
        const int nrow = row + MGRID;
        const size_t rbase = (size_t)row * R_TOT;
        float2* o2 = (float2*)(out + rbase);
        const int b = row / S_LEN;
        const int i = row - b * S_LEN;
        const int t0 = ctype[row];  // block-uniform

        // ---- prefetch next row's stream (independent; hides under this row) ----
        float2 n0 = make_float2(0.f, 0.f), n1 = n0, n2 = n0;
        if (nrow < NROWS) {
            const float2* ns2 = (const float2*)(scores + (size_t)nrow * R_TOT);
            n0 = ns2[tid];
            n1 = ns2[tid + 256];
            if (tid < 69) n2 = ns2[tid + 512];
        }

        if (t0 == 0 || t0 == 2 || t0 == 7) {
            // ---- copy path: all masks all-true, zero barriers ----
            o2[tid] = r0;
            o2[tid + 256] = r1;
            if (tid < 69) o2[tid + 512] = r2;
        } else {
            // ================= verbatim round-3 state phase =================
            if (tid < 128) {
                // measure candidates: cols 2*tid, 2*tid+1 (first index wins ties)
                const bool sec = (r0.y > r0.x);
                s_val[tid] = sec ? r0.y : r0.x;
                s_idx[tid] = 2 * tid + (sec ? 1 : 0);
            } else if (tid < 136) {
                // beat candidates: beat-relative cols 2*(tid-128), +1
                const bool sec = (r0.y > r0.x);
                sb_val[tid - 128] = sec ? r0.y : r0.x;
                sb_idx[tid - 128] = (2 * tid - 256) + (sec ? 1 : 0);
            } else if (tid < 142) {
                const int w = tid - 136;
                const int e = min(i + 1, S_LEN - 1);
                const unsigned lw = local[((size_t)b * S_LEN + e) * 6 + w];
                const unsigned cw = carry[((size_t)b * NCHUNK + (e >> 8)) * 6 + w];
                unsigned v;
                if (w == 0) {
                    const unsigned ks = ((lw >> 24) & 1u) ? (lw & 0xFFu) : (cw & 0xFFu);
                    const unsigned ts = ((lw >> 25) & 1u) ? ((lw >> 8) & 0xFFu) : ((cw >> 8) & 0xFFu);
                    const unsigned tp = ((lw >> 26) & 1u) ? ((lw >> 16) & 0xFFu) : ((cw >> 16) & 0xFFu);
                    const unsigned hks = ((lw >> 24) | (cw >> 24)) & 1u;
                    const unsigned hts = ((lw >> 25) | (cw >> 25)) & 1u;
                    v = ks | (ts << 8) | (tp << 16) | (hks << 24) | (hts << 25);
                } else {
                    v = lw | cw;
                }
                s_info[w] = (int)v;
            } else if (tid < 146) {
                const int* srow = song + (size_t)row * 11;
                if (tid == 142) s_info[6] = srow[1];
                if (tid == 143) s_info[7] = srow[2];
                if (tid == 144) s_info[8] = srow[3];
                if (tid == 145) s_info[9] = ctype[row];
            }
            __syncthreads();

            // 7-barrier tree: only the t==3 path consumes pred_m/pred_b.
            if (t0 == 3) {
                for (int s = 64; s > 0; s >>= 1) {
                    if (tid < s) {
                        if (s_val[tid + s] > s_val[tid]) {  // strict > keeps lower index
                            s_val[tid] = s_val[tid + s];
                            s_idx[tid] = s_idx[tid + s];
                        }
                    }
                    __syncthreads();
                }
            }

            if (tid == 0) {
                int pred_m = -1, pred_b = -1;  // t!=3: never matches song fields (>=0)
                if (t0 == 3) {
                    pred_m = s_idx[0];
                    float bv = sb_val[0];
                    pred_b = sb_idx[0];
#pragma unroll
                    for (int q = 1; q < 8; q++) {
                        if (sb_val[q] > bv) { bv = sb_val[q]; pred_b = sb_idx[q]; }
                    }
                }
                const unsigned pack = (unsigned)s_info[0];
                const int song1 = s_info[6], song2 = s_info[7], song3 = s_info[8];
                const int t = s_info[9];
                const bool c1 = (pred_m == song1);
                const int min_beat = c1 ? song2 : 0;
                const bool c2 = c1 && (pred_b == min_beat);
                const int min_pos = c2 ? song3 : 0;
                const int last_ks = pack & 0xFF;
                const int last_ts = (pack >> 8) & 0xFF;
                const int last_tp = (pack >> 16) & 0xFF;
                f_info[0] = t;
                f_info[1] = song1;       // min_measure
                f_info[2] = min_beat;
                f_info[3] = min_pos;
                f_info[4] = (song2 == 0 && song3 == 0) ? song1 : song1 + 1;  // min_m46
                f_info[5] = d_numerators[last_ts % 12];                      // max_beat
                f_info[6] = last_ks;
                f_info[7] = last_ts;
                f_info[8] = last_tp;
                f_info[9]  = (int)((pack >> 24) & 1u);  // has_ks
                f_info[10] = (int)((pack >> 25) & 1u);  // has_ts
                const unsigned u = (unsigned)s_info[1] | (unsigned)s_info[2] | (unsigned)s_info[3] |
                                   (unsigned)s_info[4] | (unsigned)s_info[5];
                f_info[11] = (u != 0u);                 // has_inst
                f_info[12] = s_info[1]; f_info[13] = s_info[2]; f_info[14] = s_info[3];
                f_info[15] = s_info[4]; f_info[16] = s_info[5];
            }
            __syncthreads();

            const int t = f_info[0];
            const int min_measure = f_info[1], min_beat = f_info[2], min_pos = f_info[3];
            const int min_m46 = f_info[4], max_beat = f_info[5];
            const int last_ks = f_info[6], last_ts = f_info[7], last_tp = f_info[8];
            const bool has_ks = f_info[9] != 0, has_ts = f_info[10] != 0, has_inst = f_info[11] != 0;
            unsigned inst[5];
#pragma unroll
            for (int w = 0; w < 5; w++) inst[w] = (unsigned)f_info[12 + w];
            const bool is3 = (t == 3);
            const bool is46 = (t >= 4) && (t <= 6);

            // Range offsets: measure 0..256, beat 256..272, position 272..400,
            // duration 400..528, pitch 528..784, instrument 784..913,
            // velocity 913..1041, key_sign 1041..1065, time_sign 1065..1113,
            // tempo 1113..1162
            auto maskf = [&](int col) -> bool {
                if (col < 256) {
                    if (is3) return col >= min_measure;
                    if (is46) return col >= min_m46;
                    return true;
                } else if (col < 272) {
                    if (!is3) return true;
                    const int v = col - 256;
                    return (v >= min_beat) && (v < max_beat);
                } else if (col < 400) {
                    return is3 ? ((col - 272) >= min_pos) : true;
                } else if (col < 784) {
                    return true;  // duration + pitch
                } else if (col < 913) {
                    const int v = col - 784;
                    const bool pres = ((inst[v >> 5] >> (v & 31)) & 1u) != 0u;
                    if (is3) return pres;
                    if (t == 1) return has_inst ? !pres : true;
                    return true;
                } else if (col < 1041) {
                    return true;  // velocity
                } else if (col < 1065) {
                    const int v = col - 1041;
                    if (is3) return v == last_ks;
                    if (t == 4) return has_ks ? (v != last_ks) : true;
                    return true;
                } else if (col < 1113) {
                    const int v = col - 1065;
                    if (is3) return v == last_ts;
                    if (t == 5) return has_ts ? (v != last_ts) : true;
                    return true;
                } else {
                    const int v = col - 1113;
                    if (is3) return v == last_tp;
                    if (t == 6) return v != last_tp;  // no has-check for tempo
                    return true;
                }
            };

            float2 w;
            int c = 2 * tid;
            w.x = maskf(c)     ? r0.x : NEGV;
            w.y = maskf(c + 1) ? r0.y : NEGV;
            o2[tid] = w;

            c = 512 + 2 * tid;
            w.x = maskf(c)     ? r1.x : NEGV;
            w.y = maskf(c + 1) ? r1.y : NEGV;
            o2[tid + 256] = w;

            if (tid < 69) {
                c = 1024 + 2 * tid;
                w.x = maskf(c)     ? r2.x : NEGV;
                w.y = maskf(c + 1) ? r2.y : NEGV;
                o2[tid + 512] = w;
            }

            __syncthreads();  // protect LDS (s_*/f_info) for the next iteration
        }

        r0 = n0; r1 = n1; r2 = n2;
        row = nrow;
    }
}

extern "C" void kernel_launch(void* const* d_in, const int* in_sizes, int n_in,
                              void* d_out, int out_size, void* d_ws, size_t ws_size,
                              hipStream_t stream) {
    const int* song = (const int*)d_in[0];
    const int* ctype = (const int*)d_in[1];
    const float* scores = (const float*)d_in[2];
    float* out = (float*)d_out;
    unsigned* local = (unsigned*)d_ws;                          // 393,024 B
    unsigned* carry = (unsigned*)((char*)d_ws + CARRY_OFF);     // 1,536 B

    scan_local<<<BATCH * NCHUNK, 256, 0, stream>>>(song, local);
    scan_carry<<<1, 64, 0, stream>>>(song, local, carry);
    mask_kernel<<<MGRID, 256, 0, stream>>>(song, ctype, scores, local, carry, out);
}

// Round 7
// 144.728 us; speedup vs baseline: 1.1901x; 1.0892x over previous
//
#include <hip/hip_runtime.h>
#include <cstdint>
#include <cstddef>

#define S_LEN 2047
#define BATCH 8
#define R_TOT 1162
#define NCHUNK 8
#define NEGV (-1e9f)

// ws layout: local = 8*2047*6*4 = 393,024 B at offset 0. (scan_carry kernel
// removed — mask_kernel folds the <=7 chunk-end aggregates inline; they are
// the same L2-hot lines for every row of a batch.)

__device__ __constant__ int d_numerators[12] = {1, 2, 3, 4, 5, 6, 7, 8, 9, 10, 12, 16};

// ---------------------------------------------------------------------------
// Kernel 1: within-chunk inclusive scan (64 blocks = 8 batches x 8 chunks).
// VERBATIM verified (rounds 0/3).
// ---------------------------------------------------------------------------
__global__ __launch_bounds__(256) void scan_local(const int* __restrict__ song,
                                                  unsigned* __restrict__ local) {
    const int b = blockIdx.x >> 3;
    const int c = blockIdx.x & 7;
    const int tid = threadIdx.x;
    const int j = c * 256 + tid;
    __shared__ unsigned lds_f[3][256];
    __shared__ unsigned lds_inst[5][256];
    const unsigned HAS = 1u << 16;
    const long base = (long)b * S_LEN;

    unsigned e_f[3] = {0, 0, 0};
    unsigned e_inst[5] = {0, 0, 0, 0, 0};
    if (j < S_LEN) {
        const int* rj = song + (base + j) * 11;
        const int type = rj[0];
        if (type == 4)      e_f[0] = HAS | (unsigned)rj[8];
        else if (type == 5) e_f[1] = HAS | (unsigned)rj[9];
        else if (type == 6) e_f[2] = HAS | (unsigned)rj[10];
        else if (type == 1) { const int v = rj[6]; e_inst[v >> 5] = 1u << (v & 31); }
    }
#pragma unroll
    for (int w = 0; w < 3; w++) lds_f[w][tid] = e_f[w];
#pragma unroll
    for (int w = 0; w < 5; w++) lds_inst[w][tid] = e_inst[w];
    __syncthreads();

    for (int off = 1; off < 256; off <<= 1) {
        unsigned p_f[3] = {0, 0, 0};
        unsigned p_inst[5] = {0, 0, 0, 0, 0};
        if (tid >= off) {
#pragma unroll
            for (int w = 0; w < 3; w++) p_f[w] = lds_f[w][tid - off];
#pragma unroll
            for (int w = 0; w < 5; w++) p_inst[w] = lds_inst[w][tid - off];
        }
        __syncthreads();
        if (tid >= off) {
#pragma unroll
            for (int w = 0; w < 3; w++) {
                if (!(e_f[w] & HAS)) e_f[w] = p_f[w];
                lds_f[w][tid] = e_f[w];
            }
#pragma unroll
            for (int w = 0; w < 5; w++) {
                e_inst[w] |= p_inst[w];
                lds_inst[w][tid] = e_inst[w];
            }
        }
        __syncthreads();
    }

    if (j < S_LEN) {
        const unsigned w0 =
            (e_f[0] & 0xFFu) | ((e_f[1] & 0xFFu) << 8) | ((e_f[2] & 0xFFu) << 16) |
            (((e_f[0] >> 16) & 1u) << 24) | (((e_f[1] >> 16) & 1u) << 25) |
            (((e_f[2] >> 16) & 1u) << 26);
        unsigned* sp = local + (size_t)(base + j) * 6;
        sp[0] = w0;
#pragma unroll
        for (int w = 0; w < 5; w++) sp[1 + w] = e_inst[w];
    }
}

// ---------------------------------------------------------------------------
// Kernel 2: round-3 VERIFIED mask kernel, one surgical change: the 6-thread
// state-load branch (tid 136..141) folds the exclusive per-chunk carry inline
// from local[] chunk-end aggregates (byte-identical math to the removed
// scan_carry kernel: defaults song[b,0,{8,9,10}], has-bit select for ks/ts/tp,
// OR for inst words), then applies the verbatim lw/cw combine. Everything
// else is byte-identical to round 3:
//   t in {0,2,7}: pure copy, return before any barrier.
//   t != 3      : skip the 7-barrier argmax tree.
//   t == 3      : full verified path.
// ---------------------------------------------------------------------------
__global__ __launch_bounds__(256) void mask_kernel(const int* __restrict__ song,
                                                   const int* __restrict__ ctype,
                                                   const float* __restrict__ scores,
                                                   const unsigned* __restrict__ local,
                                                   float* __restrict__ out) {
    const int row = blockIdx.x;
    const int tid = threadIdx.x;
    const int b = row / S_LEN;
    const int i = row - b * S_LEN;

    __shared__ float s_val[128];
    __shared__ int   s_idx[128];
    __shared__ float sb_val[8];
    __shared__ int   sb_idx[8];
    __shared__ int   s_info[10];
    __shared__ int   f_info[17];

    const size_t rbase = (size_t)row * R_TOT;
    const float2* s2 = (const float2*)(scores + rbase);
    float2* o2 = (float2*)(out + rbase);

    const int t0 = ctype[row];  // wave-uniform scalar load; block-uniform branch

    const float2 r0 = s2[tid];
    const float2 r1 = s2[tid + 256];
    float2 r2 = make_float2(0.f, 0.f);
    if (tid < 69) r2 = s2[tid + 512];

    // ---- fast path: all masks all-true -> straight copy, zero barriers ----
    if (t0 == 0 || t0 == 2 || t0 == 7) {
        o2[tid] = r0;
        o2[tid + 256] = r1;
        if (tid < 69) o2[tid + 512] = r2;
        return;
    }

    if (tid < 128) {
        // measure candidates: cols 2*tid, 2*tid+1 (first index wins ties)
        const bool sec = (r0.y > r0.x);
        s_val[tid] = sec ? r0.y : r0.x;
        s_idx[tid] = 2 * tid + (sec ? 1 : 0);
    } else if (tid < 136) {
        // beat candidates: beat-relative cols 2*(tid-128), +1
        const bool sec = (r0.y > r0.x);
        sb_val[tid - 128] = sec ? r0.y : r0.x;
        sb_idx[tid - 128] = (2 * tid - 256) + (sec ? 1 : 0);
    } else if (tid < 142) {
        const int w = tid - 136;
        const int e = min(i + 1, S_LEN - 1);
        const int ch = e >> 8;  // fold aggregates of chunks [0, ch)
        const unsigned lw = local[((size_t)b * S_LEN + e) * 6 + w];
        unsigned v;
        if (w == 0) {
            // inline scan_carry fold, word 0 (verbatim math)
            const int* r0p = song + (size_t)b * S_LEN * 11;
            unsigned cks = (unsigned)r0p[8], cts = (unsigned)r0p[9], ctp = (unsigned)r0p[10];
            unsigned chas = 0;
            for (int cc = 0; cc < ch; cc++) {
                const unsigned a0 = local[((size_t)b * S_LEN + ((cc + 1) * 256 - 1)) * 6];
                if ((a0 >> 24) & 1u) cks = a0 & 0xFFu;
                if ((a0 >> 25) & 1u) cts = (a0 >> 8) & 0xFFu;
                if ((a0 >> 26) & 1u) ctp = (a0 >> 16) & 0xFFu;
                chas |= (a0 >> 24) & 7u;
            }
            const unsigned cw = (cks & 0xFFu) | ((cts & 0xFFu) << 8) |
                                ((ctp & 0xFFu) << 16) | (chas << 24);
            // verbatim round-3 combine
            const unsigned ks = ((lw >> 24) & 1u) ? (lw & 0xFFu) : (cw & 0xFFu);
            const unsigned ts = ((lw >> 25) & 1u) ? ((lw >> 8) & 0xFFu) : ((cw >> 8) & 0xFFu);
            const unsigned tp = ((lw >> 26) & 1u) ? ((lw >> 16) & 0xFFu) : ((cw >> 16) & 0xFFu);
            const unsigned hks = ((lw >> 24) | (cw >> 24)) & 1u;
            const unsigned hts = ((lw >> 25) | (cw >> 25)) & 1u;
            v = ks | (ts << 8) | (tp << 16) | (hks << 24) | (hts << 25);
        } else {
            // inline scan_carry fold, words 1..5: OR of chunk-end aggregates
            unsigned cw = 0;
            for (int cc = 0; cc < ch; cc++) {
                cw |= local[((size_t)b * S_LEN + ((cc + 1) * 256 - 1)) * 6 + w];
            }
            v = lw | cw;
        }
        s_info[w] = (int)v;
    } else if (tid < 146) {
        const int* srow = song + (size_t)row * 11;
        if (tid == 142) s_info[6] = srow[1];
        if (tid == 143) s_info[7] = srow[2];
        if (tid == 144) s_info[8] = srow[3];
        if (tid == 145) s_info[9] = ctype[row];
    }
    __syncthreads();

    // 7-barrier reduction tree: only the t==3 path consumes pred_m/pred_b.
    if (t0 == 3) {
        for (int s = 64; s > 0; s >>= 1) {
            if (tid < s) {
                if (s_val[tid + s] > s_val[tid]) {  // strict > keeps lower index on tie
                    s_val[tid] = s_val[tid + s];
                    s_idx[tid] = s_idx[tid + s];
                }
            }
            __syncthreads();
        }
    }

    if (tid == 0) {
        int pred_m = -1, pred_b = -1;  // t!=3: never matches song fields (>=0)
        if (t0 == 3) {
            pred_m = s_idx[0];
            float bv = sb_val[0];
            pred_b = sb_idx[0];
#pragma unroll
            for (int q = 1; q < 8; q++) {
                if (sb_val[q] > bv) { bv = sb_val[q]; pred_b = sb_idx[q]; }
            }
        }
        const unsigned pack = (unsigned)s_info[0];
        const int song1 = s_info[6], song2 = s_info[7], song3 = s_info[8];
        const int t = s_info[9];
        const bool c1 = (pred_m == song1);
        const int min_beat = c1 ? song2 : 0;
        const bool c2 = c1 && (pred_b == min_beat);
        const int min_pos = c2 ? song3 : 0;
        const int last_ks = pack & 0xFF;
        const int last_ts = (pack >> 8) & 0xFF;
        const int last_tp = (pack >> 16) & 0xFF;
        f_info[0] = t;
        f_info[1] = song1;       // min_measure
        f_info[2] = min_beat;
        f_info[3] = min_pos;
        f_info[4] = (song2 == 0 && song3 == 0) ? song1 : song1 + 1;  // min_m46
        f_info[5] = d_numerators[last_ts % 12];                      // max_beat
        f_info[6] = last_ks;
        f_info[7] = last_ts;
        f_info[8] = last_tp;
        f_info[9]  = (int)((pack >> 24) & 1u);  // has_ks
        f_info[10] = (int)((pack >> 25) & 1u);  // has_ts
        const unsigned u = (unsigned)s_info[1] | (unsigned)s_info[2] | (unsigned)s_info[3] |
                           (unsigned)s_info[4] | (unsigned)s_info[5];
        f_info[11] = (u != 0u);                 // has_inst
        f_info[12] = s_info[1]; f_info[13] = s_info[2]; f_info[14] = s_info[3];
        f_info[15] = s_info[4]; f_info[16] = s_info[5];
    }
    __syncthreads();

    const int t = f_info[0];
    const int min_measure = f_info[1], min_beat = f_info[2], min_pos = f_info[3];
    const int min_m46 = f_info[4], max_beat = f_info[5];
    const int last_ks = f_info[6], last_ts = f_info[7], last_tp = f_info[8];
    const bool has_ks = f_info[9] != 0, has_ts = f_info[10] != 0, has_inst = f_info[11] != 0;
    unsigned inst[5];
#pragma unroll
    for (int w = 0; w < 5; w++) inst[w] = (unsigned)f_info[12 + w];
    const bool is3 = (t == 3);
    const bool is46 = (t >= 4) && (t <= 6);

    // Range offsets: measure 0..256, beat 256..272, position 272..400,
    // duration 400..528, pitch 528..784, instrument 784..913,
    // velocity 913..1041, key_sign 1041..1065, time_sign 1065..1113,
    // tempo 1113..1162
    auto maskf = [&](int col) -> bool {
        if (col < 256) {
            if (is3) return col >= min_measure;
            if (is46) return col >= min_m46;
            return true;
        } else if (col < 272) {
            if (!is3) return true;
            const int v = col - 256;
            return (v >= min_beat) && (v < max_beat);
        } else if (col < 400) {
            return is3 ? ((col - 272) >= min_pos) : true;
        } else if (col < 784) {
            return true;  // duration + pitch
        } else if (col < 913) {
            const int v = col - 784;
            const bool pres = ((inst[v >> 5] >> (v & 31)) & 1u) != 0u;
            if (is3) return pres;
            if (t == 1) return has_inst ? !pres : true;
            return true;
        } else if (col < 1041) {
            return true;  // velocity
        } else if (col < 1065) {
            const int v = col - 1041;
            if (is3) return v == last_ks;
            if (t == 4) return has_ks ? (v != last_ks) : true;
            return true;
        } else if (col < 1113) {
            const int v = col - 1065;
            if (is3) return v == last_ts;
            if (t == 5) return has_ts ? (v != last_ts) : true;
            return true;
        } else {
            const int v = col - 1113;
            if (is3) return v == last_tp;
            if (t == 6) return v != last_tp;  // no has-check for tempo
            return true;
        }
    };

    float2 w;
    int c = 2 * tid;
    w.x = maskf(c)     ? r0.x : NEGV;
    w.y = maskf(c + 1) ? r0.y : NEGV;
    o2[tid] = w;

    c = 512 + 2 * tid;
    w.x = maskf(c)     ? r1.x : NEGV;
    w.y = maskf(c + 1) ? r1.y : NEGV;
    o2[tid + 256] = w;

    if (tid < 69) {
        c = 1024 + 2 * tid;
        w.x = maskf(c)     ? r2.x : NEGV;
        w.y = maskf(c + 1) ? r2.y : NEGV;
        o2[tid + 512] = w;
    }
}

extern "C" void kernel_launch(void* const* d_in, const int* in_sizes, int n_in,
                              void* d_out, int out_size, void* d_ws, size_t ws_size,
                              hipStream_t stream) {
    const int* song = (const int*)d_in[0];
    const int* ctype = (const int*)d_in[1];
    const float* scores = (const float*)d_in[2];
    float* out = (float*)d_out;
    unsigned* local = (unsigned*)d_ws;  // 393,024 B

    scan_local<<<BATCH * NCHUNK, 256, 0, stream>>>(song, local);
    mask_kernel<<<BATCH * S_LEN, 256, 0, stream>>>(song, ctype, scores, local, out);
}